// Round 5
// baseline (200.302 us; speedup 1.0000x reference)
//
#include <hip/hip_runtime.h>
#include <stdint.h>

typedef unsigned short ushort_t;
typedef __attribute__((ext_vector_type(8))) __bf16 bf16x8;
typedef __attribute__((ext_vector_type(4))) float floatx4;
typedef __attribute__((ext_vector_type(2))) uint32_t uint32x2;

__device__ __forceinline__ ushort_t f2bf(float f) {
    uint32_t u = __builtin_bit_cast(uint32_t, f);
    u += 0x7fffu + ((u >> 16) & 1u);
    return (ushort_t)(u >> 16);
}

// async 16B global->LDS (deposit at ldsbase + lane*16; ldsbase wave-uniform)
typedef __attribute__((address_space(1))) const void glb_void;
typedef __attribute__((address_space(3))) void lds_void;
__device__ __forceinline__ void gld16(const void* g, void* l) {
    __builtin_amdgcn_global_load_lds((glb_void*)g, (lds_void*)l, 16, 0, 0);
}

// Q pre-scale: dh^-0.5 * log2(e) so attention softmax runs in exp2 domain.
#define QSCALE 0.18033688011112042f

// ---------------- cast: fp32 -> bf16 ----------------
__global__ void cast_kernel(const float* __restrict__ x,
                            const float* __restrict__ Wq, const float* __restrict__ Wk,
                            const float* __restrict__ Wv, const float* __restrict__ Wp,
                            ushort_t* __restrict__ xb, ushort_t* __restrict__ Wqkvb,
                            ushort_t* __restrict__ Wpb)
{
    const int64_t NX = 4194304, NW = 1048576;
    int64_t i4 = ((int64_t)blockIdx.x * blockDim.x + threadIdx.x) * 4;
    const float* src; ushort_t* dst; int64_t off;
    if (i4 < NX)            { src = x;  dst = xb;          off = i4; }
    else if (i4 < NX+NW)    { src = Wq; dst = Wqkvb;       off = i4 - NX; }
    else if (i4 < NX+2*NW)  { src = Wk; dst = Wqkvb + NW;  off = i4 - NX - NW; }
    else if (i4 < NX+3*NW)  { src = Wv; dst = Wqkvb + 2*NW;off = i4 - NX - 2*NW; }
    else                    { src = Wp; dst = Wpb;         off = i4 - NX - 3*NW; }
    float4 v = *(const float4*)(src + off);
    ushort4 o;
    o.x = f2bf(v.x); o.y = f2bf(v.y); o.z = f2bf(v.z); o.w = f2bf(v.w);
    *(ushort4*)(dst + off) = o;
}

// ---------------- bf16 GEMM: D = A @ B^T  (global_load_lds staging) ----------------
// mode 0: scatter Q,K -> [bh][s][d] (Q pre-scaled), V -> TRANSPOSED [bh][d][s]
// mode 1: fp32 out = D + bias
#define BM 128
#define BN 128
#define BK 32

__global__ __launch_bounds__(256, 3)
void gemm_bt(const ushort_t* __restrict__ A, const ushort_t* __restrict__ Bmat,
             int M, int N, int K, int mode,
             ushort_t* __restrict__ qb, ushort_t* __restrict__ kb, ushort_t* __restrict__ vtb,
             float* __restrict__ outf, const float* __restrict__ bias)
{
    __shared__ ushort_t As[BM * BK];   // 8KB, row-major, unpadded (lane-linear deposits)
    __shared__ ushort_t Bs[BN * BK];   // 8KB
    const int tid  = threadIdx.x;
    const int lane = tid & 63;
    const int wave = tid >> 6;
    const int m0 = blockIdx.x * BM;
    const int n0 = blockIdx.y * BN;
    const int wrow = (wave >> 1) * 64;
    const int wcol = (wave & 1) * 64;
    const int q_ = lane >> 4;
    const int ml = lane & 15;

    floatx4 acc[4][4];
    for (int i = 0; i < 4; i++) for (int j = 0; j < 4; j++) acc[i][j] = floatx4{0.f,0.f,0.f,0.f};

    // staging: 8 blocks of 1KB per tile (16 rows x 32 cols); wave w does blocks 2w,2w+1
    const int t0 = wave * 2, t1 = wave * 2 + 1;
    const int row_l = lane >> 2;         // 0..15
    const int col_l = (lane & 3) * 8;    // 0,8,16,24
    const ushort_t* Ag0 = A    + (int64_t)(m0 + t0*16 + row_l) * K + col_l;
    const ushort_t* Ag1 = A    + (int64_t)(m0 + t1*16 + row_l) * K + col_l;
    const ushort_t* Bg0 = Bmat + (int64_t)(n0 + t0*16 + row_l) * K + col_l;
    const ushort_t* Bg1 = Bmat + (int64_t)(n0 + t1*16 + row_l) * K + col_l;
    ushort_t* Al0 = As + t0*512; ushort_t* Al1 = As + t1*512;
    ushort_t* Bl0 = Bs + t0*512; ushort_t* Bl1 = Bs + t1*512;

    for (int k0 = 0; k0 < K; k0 += BK) {
        __syncthreads();
        gld16(Ag0 + k0, Al0);
        gld16(Ag1 + k0, Al1);
        gld16(Bg0 + k0, Bl0);
        gld16(Bg1 + k0, Bl1);
        __syncthreads();
        bf16x8 af[4], bf[4];
        for (int mt = 0; mt < 4; mt++)
            af[mt] = *(const bf16x8*)(As + (wrow + mt*16 + ml) * BK + q_*8);
        for (int nt = 0; nt < 4; nt++)
            bf[nt] = *(const bf16x8*)(Bs + (wcol + nt*16 + ml) * BK + q_*8);
        for (int mt = 0; mt < 4; mt++)
            for (int nt = 0; nt < 4; nt++)
                acc[mt][nt] = __builtin_amdgcn_mfma_f32_16x16x32_bf16(af[mt], bf[nt], acc[mt][nt], 0, 0, 0);
    }

    if (mode == 0) {
        for (int mt = 0; mt < 4; mt++) for (int nt = 0; nt < 4; nt++) {
            floatx4 v = acc[mt][nt];
            int col = n0 + wcol + nt*16 + ml;
            int which = col >> 10;
            int nn = col & 1023;
            int h = nn >> 6, d = nn & 63;
            if (which < 2) {
                ushort_t* dst = (which == 0) ? qb : kb;
                float sc = (which == 0) ? QSCALE : 1.0f;
                for (int r = 0; r < 4; r++) {
                    int rowg = m0 + wrow + mt*16 + q_*4 + r;
                    int b = rowg >> 11, s = rowg & 2047;
                    dst[(((int64_t)(b*16 + h) * 2048 + s) << 6) + d] = f2bf(v[r] * sc);
                }
            } else {
                int rowg0 = m0 + wrow + mt*16 + q_*4;
                int b = rowg0 >> 11, sbase = rowg0 & 2047;
                ushort4 o;
                o.x = f2bf(v[0]); o.y = f2bf(v[1]); o.z = f2bf(v[2]); o.w = f2bf(v[3]);
                *(ushort4*)(vtb + (((int64_t)(b*16 + h) * 64 + d) << 11) + sbase) = o;
            }
        }
    } else {
        for (int mt = 0; mt < 4; mt++) for (int nt = 0; nt < 4; nt++) {
            floatx4 v = acc[mt][nt];
            int col = n0 + wcol + nt*16 + ml;
            float bv = bias[col];
            for (int r = 0; r < 4; r++) {
                int rowg = m0 + wrow + mt*16 + q_*4 + r;
                outf[(int64_t)rowg * N + col] = v[r] + bv;
            }
        }
    }
}

// ---------------- fused masked flash attention, 2 waves x 32 q-rows ----------------
// Pipelined chunk loop (T3/T14): K double-buffered (issue K(t+1) a full chunk
// early), V single-buffered (issued right after PV(t-1), waited at chunk top).
// vmcnt(8) at chunk top = everything except the 8 newest (K(t+1)) is done ->
// both K(t) and V(t) ready; never vmcnt(0) mid-loop. 2 raw barriers per chunk.
// Swapped QK^T (verified r3/r4): lane holds P[q=ml][k=kt*16+4*q_+r] -> b64 P
// stores; data path byte-identical to r4. LDS 66,560B -> 2 blocks/CU; grid
// 1024 (heavy views first) for tail backfill.
__global__ __launch_bounds__(128, 2)
void attn_kernel(const ushort_t* __restrict__ Q, const ushort_t* __restrict__ Kb,
                 const ushort_t* __restrict__ Vt, ushort_t* __restrict__ Out)
{
    __shared__ ushort_t Kd[2][8192];     // 2 x 16KB K tiles (lane-linear 1KB blocks)
    __shared__ ushort_t Vl[8192];        // 16KB V tile
    __shared__ ushort_t Pl[2 * 32 * 136];// per-wave P tile [32 q][128 k], stride 136

    int bi = blockIdx.x;                 // 1024 blocks
    int bh  = (bi & 7) + 8 * ((bi >> 3) & 3);   // low 3 bits -> XCD spread
    int qt2 = (bi >> 5) & 3;             // 64-row q tile
    int g8  = bi >> 7;                   // dispatch group, heavy first
    int qv  = (g8 < 6) ? (7 - g8) : (g8 - 6);   // {7,6,5,4,3,2,0,1}
    int b = bh >> 4, h = bh & 15;
    int tid = threadIdx.x;
    int wave = tid >> 6, lane = tid & 63;
    int q_ = lane >> 4, ml = lane & 15;
    int rlane = lane & 15, clane = lane >> 4;
    int s0 = qv*256 + qt2*64 + wave*32;  // this wave's 32 q-rows

    const ushort_t* Kbh = Kb + ((int64_t)bh << 17);
    const ushort_t* Vbh = Vt + ((int64_t)bh << 17);
    ushort_t* Pw = Pl + wave * (32 * 136);

    const ushort_t* Qp = Q + (((int64_t)bh*2048 + s0 + ml) << 6) + q_*8;
    bf16x8 aq0A = *(const bf16x8*)(Qp);
    bf16x8 aq1A = *(const bf16x8*)(Qp + 32);
    bf16x8 aq0B = *(const bf16x8*)(Qp + 1024);        // +16 rows
    bf16x8 aq1B = *(const bf16x8*)(Qp + 1024 + 32);

    floatx4 o_accA[4], o_accB[4];
    for (int i = 0; i < 4; i++) { o_accA[i] = floatx4{0.f,0.f,0.f,0.f};
                                  o_accB[i] = floatx4{0.f,0.f,0.f,0.f}; }
    float lsumA = 0.f, lsumB = 0.f;

    const int nviews = (qv < 2) ? 1 : (qv + 1);
    const int NT = nviews * 2;
    const int vfix = qv ^ 1;             // the single view when nviews==1

    // per-wave staging: 8 K ids + 8 V ids (ids wave*8 .. wave*8+7 of 16)
    // K id: row (id>>1)*16 + rlane, col (id&1)*32 + clane*8 -> Kd[.] + id*512
    // V id: row (id&3)*16 + rlane,  col (id>>2)*32 + clane*8 -> Vl + id*512

    // ---- prologue: stage chunk 0 (K then V; order matters for vmcnt) ----
    {
        int vw = (nviews == 1) ? vfix : 0;
        int koff = vw * 256;
        #pragma unroll
        for (int i = 0; i < 8; i++) {
            int id = wave*8 + i;
            const ushort_t* gk = Kbh + (((int64_t)(koff + (id >> 1)*16 + rlane)) << 6)
                                     + (id & 1)*32 + clane*8;
            gld16(gk, Kd[0] + id*512);
        }
        #pragma unroll
        for (int i = 0; i < 8; i++) {
            int id = wave*8 + i;
            const ushort_t* gv = Vbh + ((int64_t)((id & 3)*16 + rlane) << 11)
                                     + koff + (id >> 2)*32 + clane*8;
            gld16(gv, Vl + id*512);
        }
    }

    for (int t = 0; t < NT; ++t) {
        int cur = t & 1;
        int koff = ((nviews == 1) ? vfix : (t >> 1)) * 256 + (t & 1) * 128;

        if (t + 1 < NT) {
            // issue next chunk's K into the other buffer (readers finished 2 barriers ago)
            int koff_n = ((nviews == 1) ? vfix : ((t + 1) >> 1)) * 256 + ((t + 1) & 1) * 128;
            #pragma unroll
            for (int i = 0; i < 8; i++) {
                int id = wave*8 + i;
                const ushort_t* gk = Kbh + (((int64_t)(koff_n + (id >> 1)*16 + rlane)) << 6)
                                         + (id & 1)*32 + clane*8;
                gld16(gk, Kd[cur ^ 1] + id*512);
            }
            // newest 8 = K(t+1); everything older (K(t), V(t)) must be done
            asm volatile("s_waitcnt vmcnt(8)" ::: "memory");
        } else {
            asm volatile("s_waitcnt vmcnt(0)" ::: "memory");
        }
        __builtin_amdgcn_s_barrier();    // K(t) and V(t) visible to both waves

        // ---- S = K @ Q^T : lane -> q-row ml, keys kt*16 + 4*q_ + r ----
        const ushort_t* Kl = Kd[cur];
        #pragma unroll
        for (int kt = 0; kt < 8; kt++) {
            bf16x8 k0 = *(const bf16x8*)(Kl + kt*1024 + lane*8);
            bf16x8 k1 = *(const bf16x8*)(Kl + kt*1024 + 512 + lane*8);
            floatx4 czA = floatx4{0.f,0.f,0.f,0.f};
            floatx4 czB = floatx4{0.f,0.f,0.f,0.f};
            __builtin_amdgcn_s_setprio(1);
            czA = __builtin_amdgcn_mfma_f32_16x16x32_bf16(k0, aq0A, czA, 0, 0, 0);
            czA = __builtin_amdgcn_mfma_f32_16x16x32_bf16(k1, aq1A, czA, 0, 0, 0);
            czB = __builtin_amdgcn_mfma_f32_16x16x32_bf16(k0, aq0B, czB, 0, 0, 0);
            czB = __builtin_amdgcn_mfma_f32_16x16x32_bf16(k1, aq1B, czB, 0, 0, 0);
            __builtin_amdgcn_s_setprio(0);

            float a0 = __builtin_amdgcn_exp2f(czA[0]);
            float a1 = __builtin_amdgcn_exp2f(czA[1]);
            float a2 = __builtin_amdgcn_exp2f(czA[2]);
            float a3 = __builtin_amdgcn_exp2f(czA[3]);
            lsumA += (a0 + a1) + (a2 + a3);
            uint32x2 wa;
            wa[0] = (uint32_t)f2bf(a0) | ((uint32_t)f2bf(a1) << 16);
            wa[1] = (uint32_t)f2bf(a2) | ((uint32_t)f2bf(a3) << 16);
            *(uint32x2*)(Pw + ml*136 + kt*16 + q_*4) = wa;           // ds_write_b64

            float b0 = __builtin_amdgcn_exp2f(czB[0]);
            float b1 = __builtin_amdgcn_exp2f(czB[1]);
            float b2 = __builtin_amdgcn_exp2f(czB[2]);
            float b3 = __builtin_amdgcn_exp2f(czB[3]);
            lsumB += (b0 + b1) + (b2 + b3);
            uint32x2 wb;
            wb[0] = (uint32_t)f2bf(b0) | ((uint32_t)f2bf(b1) << 16);
            wb[1] = (uint32_t)f2bf(b2) | ((uint32_t)f2bf(b3) << 16);
            *(uint32x2*)(Pw + (16 + ml)*136 + kt*16 + q_*4) = wb;
        }

        asm volatile("s_waitcnt lgkmcnt(0)" ::: "memory");  // wave-private P visible

        // ---- O += P @ V ----
        #pragma unroll
        for (int g = 0; g < 4; g++) {
            bf16x8 apA = *(const bf16x8*)(Pw + ml*136 + g*32 + q_*8);
            bf16x8 apB = *(const bf16x8*)(Pw + (16 + ml)*136 + g*32 + q_*8);
            __builtin_amdgcn_s_setprio(1);
            #pragma unroll
            for (int dt = 0; dt < 4; dt++) {
                bf16x8 vv = *(const bf16x8*)(Vl + (g*4 + dt)*512 + lane*8);
                o_accA[dt] = __builtin_amdgcn_mfma_f32_16x16x32_bf16(apA, vv, o_accA[dt], 0, 0, 0);
                o_accB[dt] = __builtin_amdgcn_mfma_f32_16x16x32_bf16(apB, vv, o_accB[dt], 0, 0, 0);
            }
            __builtin_amdgcn_s_setprio(0);
        }

        __builtin_amdgcn_s_barrier();    // all waves done reading Vl -> free to restage

        if (t + 1 < NT) {
            int koff_n = ((nviews == 1) ? vfix : ((t + 1) >> 1)) * 256 + ((t + 1) & 1) * 128;
            #pragma unroll
            for (int i = 0; i < 8; i++) {
                int id = wave*8 + i;
                const ushort_t* gv = Vbh + ((int64_t)((id & 3)*16 + rlane) << 11)
                                         + koff_n + (id >> 2)*32 + clane*8;
                gld16(gv, Vl + id*512);
            }
        }
    }

    // reduce l across the 4 quarters holding the same q-row (lanes ml + 16*q_)
    lsumA += __shfl_xor(lsumA, 16);
    lsumA += __shfl_xor(lsumA, 32);
    lsumB += __shfl_xor(lsumB, 16);
    lsumB += __shfl_xor(lsumB, 32);
    // o_acc rows are q = q_*4 + r; that row's total l lives at lane (q_*4 + r)
    float rinvA[4], rinvB[4];
    #pragma unroll
    for (int r = 0; r < 4; r++) {
        rinvA[r] = 1.0f / __shfl(lsumA, q_*4 + r);
        rinvB[r] = 1.0f / __shfl(lsumB, q_*4 + r);
    }

    // epilogue: Out[b][s][h*64+d] = o/l (bf16)
    #pragma unroll
    for (int dt = 0; dt < 4; dt++)
        #pragma unroll
        for (int r = 0; r < 4; r++) {
            int srA = s0 + q_*4 + r;
            Out[((int64_t)b*2048 + srA) * 1024 + h*64 + dt*16 + ml] = f2bf(o_accA[dt][r] * rinvA[r]);
            int srB = s0 + 16 + q_*4 + r;
            Out[((int64_t)b*2048 + srB) * 1024 + h*64 + dt*16 + ml] = f2bf(o_accB[dt][r] * rinvB[r]);
        }
}

extern "C" void kernel_launch(void* const* d_in, const int* in_sizes, int n_in,
                              void* d_out, int out_size, void* d_ws, size_t ws_size,
                              hipStream_t stream) {
    const float* x  = (const float*)d_in[0];
    const float* Wq = (const float*)d_in[1];
    const float* Wk = (const float*)d_in[2];
    const float* Wv = (const float*)d_in[3];
    const float* Wp = (const float*)d_in[4];
    const float* bp = (const float*)d_in[5];
    float* out = (float*)d_out;

    char* ws = (char*)d_ws;
    ushort_t* xb    = (ushort_t*)(ws);
    ushort_t* Wqkvb = (ushort_t*)(ws + ((size_t)8  << 20));
    ushort_t* Wpb   = (ushort_t*)(ws + ((size_t)14 << 20));
    ushort_t* qb    = (ushort_t*)(ws + ((size_t)16 << 20));
    ushort_t* kbuf  = (ushort_t*)(ws + ((size_t)24 << 20));
    ushort_t* vtb   = (ushort_t*)(ws + ((size_t)40 << 20));
    ushort_t* attno = xb;

    cast_kernel<<<8192, 256, 0, stream>>>(x, Wq, Wk, Wv, Wp, xb, Wqkvb, Wpb);

    dim3 g0(4096 / BM, 3072 / BN);
    gemm_bt<<<g0, 256, 0, stream>>>(xb, Wqkvb, 4096, 3072, 1024, 0,
                                    qb, kbuf, vtb, nullptr, nullptr);

    attn_kernel<<<1024, 128, 0, stream>>>(qb, kbuf, vtb, attno);

    dim3 g1(4096 / BM, 1024 / BN);
    gemm_bt<<<g1, 256, 0, stream>>>(attno, Wpb, 4096, 1024, 1024, 1,
                                    nullptr, nullptr, nullptr, out, bp);
}

// Round 7
// 192.472 us; speedup vs baseline: 1.0407x; 1.0407x over previous
//
#include <hip/hip_runtime.h>
#include <stdint.h>

typedef unsigned short ushort_t;
typedef __attribute__((ext_vector_type(8))) __bf16 bf16x8;
typedef __attribute__((ext_vector_type(4))) float floatx4;
typedef __attribute__((ext_vector_type(2))) uint32_t uint32x2;

__device__ __forceinline__ ushort_t f2bf(float f) {
    uint32_t u = __builtin_bit_cast(uint32_t, f);
    u += 0x7fffu + ((u >> 16) & 1u);
    return (ushort_t)(u >> 16);
}

// async 16B global->LDS (deposit at ldsbase + lane*16; ldsbase wave-uniform)
typedef __attribute__((address_space(1))) const void glb_void;
typedef __attribute__((address_space(3))) void lds_void;
__device__ __forceinline__ void gld16(const void* g, void* l) {
    __builtin_amdgcn_global_load_lds((glb_void*)g, (lds_void*)l, 16, 0, 0);
}

// Q pre-scale: dh^-0.5 * log2(e) so attention softmax runs in exp2 domain.
#define QSCALE 0.18033688011112042f

// ---------------- cast: fp32 -> bf16 ----------------
__global__ void cast_kernel(const float* __restrict__ x,
                            const float* __restrict__ Wq, const float* __restrict__ Wk,
                            const float* __restrict__ Wv, const float* __restrict__ Wp,
                            ushort_t* __restrict__ xb, ushort_t* __restrict__ Wqkvb,
                            ushort_t* __restrict__ Wpb)
{
    const int64_t NX = 4194304, NW = 1048576;
    int64_t i4 = ((int64_t)blockIdx.x * blockDim.x + threadIdx.x) * 4;
    const float* src; ushort_t* dst; int64_t off;
    if (i4 < NX)            { src = x;  dst = xb;          off = i4; }
    else if (i4 < NX+NW)    { src = Wq; dst = Wqkvb;       off = i4 - NX; }
    else if (i4 < NX+2*NW)  { src = Wk; dst = Wqkvb + NW;  off = i4 - NX - NW; }
    else if (i4 < NX+3*NW)  { src = Wv; dst = Wqkvb + 2*NW;off = i4 - NX - 2*NW; }
    else                    { src = Wp; dst = Wpb;         off = i4 - NX - 3*NW; }
    float4 v = *(const float4*)(src + off);
    ushort4 o;
    o.x = f2bf(v.x); o.y = f2bf(v.y); o.z = f2bf(v.z); o.w = f2bf(v.w);
    *(ushort4*)(dst + off) = o;
}

// ---------------- bf16 GEMM: D = A @ B^T  (global_load_lds staging) ----------------
// mode 0: scatter Q,K -> [bh][s][d] (Q pre-scaled), V -> TRANSPOSED [bh][d][s]
// mode 1: fp32 out = D + bias
#define BM 128
#define BN 128
#define BK 32

__global__ __launch_bounds__(256, 3)
void gemm_bt(const ushort_t* __restrict__ A, const ushort_t* __restrict__ Bmat,
             int M, int N, int K, int mode,
             ushort_t* __restrict__ qb, ushort_t* __restrict__ kb, ushort_t* __restrict__ vtb,
             float* __restrict__ outf, const float* __restrict__ bias)
{
    __shared__ ushort_t As[BM * BK];   // 8KB, row-major, unpadded (lane-linear deposits)
    __shared__ ushort_t Bs[BN * BK];   // 8KB
    const int tid  = threadIdx.x;
    const int lane = tid & 63;
    const int wave = tid >> 6;
    const int m0 = blockIdx.x * BM;
    const int n0 = blockIdx.y * BN;
    const int wrow = (wave >> 1) * 64;
    const int wcol = (wave & 1) * 64;
    const int q_ = lane >> 4;
    const int ml = lane & 15;

    floatx4 acc[4][4];
    for (int i = 0; i < 4; i++) for (int j = 0; j < 4; j++) acc[i][j] = floatx4{0.f,0.f,0.f,0.f};

    // staging: 8 blocks of 1KB per tile (16 rows x 32 cols); wave w does blocks 2w,2w+1
    const int t0 = wave * 2, t1 = wave * 2 + 1;
    const int row_l = lane >> 2;         // 0..15
    const int col_l = (lane & 3) * 8;    // 0,8,16,24
    const ushort_t* Ag0 = A    + (int64_t)(m0 + t0*16 + row_l) * K + col_l;
    const ushort_t* Ag1 = A    + (int64_t)(m0 + t1*16 + row_l) * K + col_l;
    const ushort_t* Bg0 = Bmat + (int64_t)(n0 + t0*16 + row_l) * K + col_l;
    const ushort_t* Bg1 = Bmat + (int64_t)(n0 + t1*16 + row_l) * K + col_l;
    ushort_t* Al0 = As + t0*512; ushort_t* Al1 = As + t1*512;
    ushort_t* Bl0 = Bs + t0*512; ushort_t* Bl1 = Bs + t1*512;

    for (int k0 = 0; k0 < K; k0 += BK) {
        __syncthreads();
        gld16(Ag0 + k0, Al0);
        gld16(Ag1 + k0, Al1);
        gld16(Bg0 + k0, Bl0);
        gld16(Bg1 + k0, Bl1);
        __syncthreads();
        bf16x8 af[4], bf[4];
        for (int mt = 0; mt < 4; mt++)
            af[mt] = *(const bf16x8*)(As + (wrow + mt*16 + ml) * BK + q_*8);
        for (int nt = 0; nt < 4; nt++)
            bf[nt] = *(const bf16x8*)(Bs + (wcol + nt*16 + ml) * BK + q_*8);
        for (int mt = 0; mt < 4; mt++)
            for (int nt = 0; nt < 4; nt++)
                acc[mt][nt] = __builtin_amdgcn_mfma_f32_16x16x32_bf16(af[mt], bf[nt], acc[mt][nt], 0, 0, 0);
    }

    if (mode == 0) {
        for (int mt = 0; mt < 4; mt++) for (int nt = 0; nt < 4; nt++) {
            floatx4 v = acc[mt][nt];
            int col = n0 + wcol + nt*16 + ml;
            int which = col >> 10;
            int nn = col & 1023;
            int h = nn >> 6, d = nn & 63;
            if (which < 2) {
                ushort_t* dst = (which == 0) ? qb : kb;
                float sc = (which == 0) ? QSCALE : 1.0f;
                for (int r = 0; r < 4; r++) {
                    int rowg = m0 + wrow + mt*16 + q_*4 + r;
                    int b = rowg >> 11, s = rowg & 2047;
                    dst[(((int64_t)(b*16 + h) * 2048 + s) << 6) + d] = f2bf(v[r] * sc);
                }
            } else {
                int rowg0 = m0 + wrow + mt*16 + q_*4;
                int b = rowg0 >> 11, sbase = rowg0 & 2047;
                ushort4 o;
                o.x = f2bf(v[0]); o.y = f2bf(v[1]); o.z = f2bf(v[2]); o.w = f2bf(v[3]);
                *(ushort4*)(vtb + (((int64_t)(b*16 + h) * 64 + d) << 11) + sbase) = o;
            }
        }
    } else {
        for (int mt = 0; mt < 4; mt++) for (int nt = 0; nt < 4; nt++) {
            floatx4 v = acc[mt][nt];
            int col = n0 + wcol + nt*16 + ml;
            float bv = bias[col];
            for (int r = 0; r < 4; r++) {
                int rowg = m0 + wrow + mt*16 + q_*4 + r;
                outf[(int64_t)rowg * N + col] = v[r] + bv;
            }
        }
    }
}

// ---------------- fused masked flash attention: 4 waves x 32 q-rows, pipelined ----
// r4 data path (swapped QK^T, two q-tiles per wave sharing K/V frags) + r5 loop
// skeleton (K double-buffered, issued a full chunk early; V single-buffered,
// issued post-PV-barrier; counted vmcnt(4) at chunk top — never vmcnt(0) mid-loop).
// P LDS is 16 rows/wave: tile B's packed P words live in 16 regs through PV-A,
// then reuse the same wave-private P rows (same-wave DS ordering makes the
// write-after-read safe). LDS 66,560B -> 2 blocks/CU -> 8 waves/CU (2/SIMD).
__global__ __launch_bounds__(256, 2)
void attn_kernel(const ushort_t* __restrict__ Q, const ushort_t* __restrict__ Kb,
                 const ushort_t* __restrict__ Vt, ushort_t* __restrict__ Out)
{
    __shared__ ushort_t Kd[2][8192];     // 2 x 16KB K tiles (lane-linear 1KB blocks)
    __shared__ ushort_t Vl[8192];        // 16KB V tile
    __shared__ ushort_t Pl[4 * 16 * 136];// per-wave P tile [16 q][128 k], stride 136

    int bi = blockIdx.x;                 // 512 blocks
    int bh = (bi & 7) + 8 * ((bi >> 3) & 3);   // low 3 bits -> XCD spread
    int qt = (bi >> 5) & 1;
    int g8 = bi >> 6;                    // dispatch group, heavy first
    int qv = (g8 < 4) ? (7 - g8) : (g8 - 4);   // {7,6,5,4,0,1,2,3}
    int b = bh >> 4, h = bh & 15;
    int tid = threadIdx.x;
    int wave = tid >> 6, lane = tid & 63;
    int q_ = lane >> 4, ml = lane & 15;
    int rlane = lane & 15, clane = lane >> 4;
    int s0 = qv*256 + qt*128 + wave*32;  // this wave's 32 q-rows

    const ushort_t* Kbh = Kb + ((int64_t)bh << 17);
    const ushort_t* Vbh = Vt + ((int64_t)bh << 17);
    ushort_t* Pw = Pl + wave * (16 * 136);

    const ushort_t* Qp = Q + (((int64_t)bh*2048 + s0 + ml) << 6) + q_*8;
    bf16x8 aq0A = *(const bf16x8*)(Qp);
    bf16x8 aq1A = *(const bf16x8*)(Qp + 32);
    bf16x8 aq0B = *(const bf16x8*)(Qp + 1024);        // +16 rows
    bf16x8 aq1B = *(const bf16x8*)(Qp + 1024 + 32);

    floatx4 o_accA[4], o_accB[4];
    for (int i = 0; i < 4; i++) { o_accA[i] = floatx4{0.f,0.f,0.f,0.f};
                                  o_accB[i] = floatx4{0.f,0.f,0.f,0.f}; }
    float lsumA = 0.f, lsumB = 0.f;

    const int nviews = (qv < 2) ? 1 : (qv + 1);
    const int NT = nviews * 2;
    const int vfix = qv ^ 1;             // the single view when nviews==1

    // per-wave staging: 4 K ids + 4 V ids (ids wave*4 .. wave*4+3 of 16)
    // K id: row (id>>1)*16 + rlane, col (id&1)*32 + clane*8 -> Kd[.] + id*512
    // V id: row (id&3)*16 + rlane,  col (id>>2)*32 + clane*8 -> Vl + id*512

    // ---- prologue: stage chunk 0 (K then V; issue order matters for vmcnt) ----
    {
        int koff = ((nviews == 1) ? vfix : 0) * 256;
        #pragma unroll
        for (int i = 0; i < 4; i++) {
            int id = wave*4 + i;
            const ushort_t* gk = Kbh + (((int64_t)(koff + (id >> 1)*16 + rlane)) << 6)
                                     + (id & 1)*32 + clane*8;
            gld16(gk, Kd[0] + id*512);
        }
        #pragma unroll
        for (int i = 0; i < 4; i++) {
            int id = wave*4 + i;
            const ushort_t* gv = Vbh + ((int64_t)((id & 3)*16 + rlane) << 11)
                                     + koff + (id >> 2)*32 + clane*8;
            gld16(gv, Vl + id*512);
        }
    }

    for (int t = 0; t < NT; ++t) {
        int cur = t & 1;

        if (t + 1 < NT) {
            // issue next chunk's K into the other buffer (its readers finished
            // before the previous chunk's second barrier)
            int koff_n = ((nviews == 1) ? vfix : ((t + 1) >> 1)) * 256 + ((t + 1) & 1) * 128;
            #pragma unroll
            for (int i = 0; i < 4; i++) {
                int id = wave*4 + i;
                const ushort_t* gk = Kbh + (((int64_t)(koff_n + (id >> 1)*16 + rlane)) << 6)
                                         + (id & 1)*32 + clane*8;
                gld16(gk, Kd[cur ^ 1] + id*512);
            }
            // newest 4 = K(t+1); everything older (K(t), V(t)) must be done
            asm volatile("s_waitcnt vmcnt(4)" ::: "memory");
        } else {
            asm volatile("s_waitcnt vmcnt(0)" ::: "memory");
        }
        __builtin_amdgcn_s_barrier();    // K(t) and V(t) visible to all waves

        // ---- S = K @ Q^T : lane -> q-row ml, keys kt*16 + 4*q_ + r ----
        const ushort_t* Kl = Kd[cur];
        uint32_t pb[16];                 // tile B packed P (static-indexed regs)
        #pragma unroll
        for (int kt = 0; kt < 8; kt++) {
            bf16x8 k0 = *(const bf16x8*)(Kl + kt*1024 + lane*8);
            bf16x8 k1 = *(const bf16x8*)(Kl + kt*1024 + 512 + lane*8);
            floatx4 czA = floatx4{0.f,0.f,0.f,0.f};
            floatx4 czB = floatx4{0.f,0.f,0.f,0.f};
            __builtin_amdgcn_s_setprio(1);
            czA = __builtin_amdgcn_mfma_f32_16x16x32_bf16(k0, aq0A, czA, 0, 0, 0);
            czA = __builtin_amdgcn_mfma_f32_16x16x32_bf16(k1, aq1A, czA, 0, 0, 0);
            czB = __builtin_amdgcn_mfma_f32_16x16x32_bf16(k0, aq0B, czB, 0, 0, 0);
            czB = __builtin_amdgcn_mfma_f32_16x16x32_bf16(k1, aq1B, czB, 0, 0, 0);
            __builtin_amdgcn_s_setprio(0);

            float a0 = __builtin_amdgcn_exp2f(czA[0]);
            float a1 = __builtin_amdgcn_exp2f(czA[1]);
            float a2 = __builtin_amdgcn_exp2f(czA[2]);
            float a3 = __builtin_amdgcn_exp2f(czA[3]);
            lsumA += (a0 + a1) + (a2 + a3);
            uint32x2 wa;
            wa[0] = (uint32_t)f2bf(a0) | ((uint32_t)f2bf(a1) << 16);
            wa[1] = (uint32_t)f2bf(a2) | ((uint32_t)f2bf(a3) << 16);
            *(uint32x2*)(Pw + ml*136 + kt*16 + q_*4) = wa;           // ds_write_b64

            float b0 = __builtin_amdgcn_exp2f(czB[0]);
            float b1 = __builtin_amdgcn_exp2f(czB[1]);
            float b2 = __builtin_amdgcn_exp2f(czB[2]);
            float b3 = __builtin_amdgcn_exp2f(czB[3]);
            lsumB += (b0 + b1) + (b2 + b3);
            pb[kt*2    ] = (uint32_t)f2bf(b0) | ((uint32_t)f2bf(b1) << 16);
            pb[kt*2 + 1] = (uint32_t)f2bf(b2) | ((uint32_t)f2bf(b3) << 16);
        }

        asm volatile("s_waitcnt lgkmcnt(0)" ::: "memory");  // wave-private P_A visible

        // ---- O_A += P_A @ V ----
        #pragma unroll
        for (int g = 0; g < 4; g++) {
            bf16x8 apA = *(const bf16x8*)(Pw + ml*136 + g*32 + q_*8);
            __builtin_amdgcn_s_setprio(1);
            #pragma unroll
            for (int dt = 0; dt < 4; dt++) {
                bf16x8 vv = *(const bf16x8*)(Vl + (g*4 + dt)*512 + lane*8);
                o_accA[dt] = __builtin_amdgcn_mfma_f32_16x16x32_bf16(apA, vv, o_accA[dt], 0, 0, 0);
            }
            __builtin_amdgcn_s_setprio(0);
        }

        // ---- store P_B into the same wave-private rows (same-wave DS order) ----
        #pragma unroll
        for (int kt = 0; kt < 8; kt++) {
            uint32x2 wb; wb[0] = pb[kt*2]; wb[1] = pb[kt*2 + 1];
            *(uint32x2*)(Pw + ml*136 + kt*16 + q_*4) = wb;
        }
        asm volatile("s_waitcnt lgkmcnt(0)" ::: "memory");  // P_B visible

        // ---- O_B += P_B @ V ----
        #pragma unroll
        for (int g = 0; g < 4; g++) {
            bf16x8 apB = *(const bf16x8*)(Pw + ml*136 + g*32 + q_*8);
            __builtin_amdgcn_s_setprio(1);
            #pragma unroll
            for (int dt = 0; dt < 4; dt++) {
                bf16x8 vv = *(const bf16x8*)(Vl + (g*4 + dt)*512 + lane*8);
                o_accB[dt] = __builtin_amdgcn_mfma_f32_16x16x32_bf16(apB, vv, o_accB[dt], 0, 0, 0);
            }
            __builtin_amdgcn_s_setprio(0);
        }

        __builtin_amdgcn_s_barrier();    // all waves done reading Vl/K(t)

        if (t + 1 < NT) {
            int koff_n = ((nviews == 1) ? vfix : ((t + 1) >> 1)) * 256 + ((t + 1) & 1) * 128;
            #pragma unroll
            for (int i = 0; i < 4; i++) {
                int id = wave*4 + i;
                const ushort_t* gv = Vbh + ((int64_t)((id & 3)*16 + rlane) << 11)
                                         + koff_n + (id >> 2)*32 + clane*8;
                gld16(gv, Vl + id*512);
            }
        }
    }

    // reduce l across the 4 quarters holding the same q-row (lanes ml + 16*q_)
    lsumA += __shfl_xor(lsumA, 16);
    lsumA += __shfl_xor(lsumA, 32);
    lsumB += __shfl_xor(lsumB, 16);
    lsumB += __shfl_xor(lsumB, 32);
    // o_acc rows are q = q_*4 + r; that row's total l lives at lane (q_*4 + r)
    float rinvA[4], rinvB[4];
    #pragma unroll
    for (int r = 0; r < 4; r++) {
        rinvA[r] = 1.0f / __shfl(lsumA, q_*4 + r);
        rinvB[r] = 1.0f / __shfl(lsumB, q_*4 + r);
    }

    // epilogue: Out[b][s][h*64+d] = o/l (bf16)
    #pragma unroll
    for (int dt = 0; dt < 4; dt++)
        #pragma unroll
        for (int r = 0; r < 4; r++) {
            int srA = s0 + q_*4 + r;
            Out[((int64_t)b*2048 + srA) * 1024 + h*64 + dt*16 + ml] = f2bf(o_accA[dt][r] * rinvA[r]);
            int srB = s0 + 16 + q_*4 + r;
            Out[((int64_t)b*2048 + srB) * 1024 + h*64 + dt*16 + ml] = f2bf(o_accB[dt][r] * rinvB[r]);
        }
}

extern "C" void kernel_launch(void* const* d_in, const int* in_sizes, int n_in,
                              void* d_out, int out_size, void* d_ws, size_t ws_size,
                              hipStream_t stream) {
    const float* x  = (const float*)d_in[0];
    const float* Wq = (const float*)d_in[1];
    const float* Wk = (const float*)d_in[2];
    const float* Wv = (const float*)d_in[3];
    const float* Wp = (const float*)d_in[4];
    const float* bp = (const float*)d_in[5];
    float* out = (float*)d_out;

    char* ws = (char*)d_ws;
    ushort_t* xb    = (ushort_t*)(ws);
    ushort_t* Wqkvb = (ushort_t*)(ws + ((size_t)8  << 20));
    ushort_t* Wpb   = (ushort_t*)(ws + ((size_t)14 << 20));
    ushort_t* qb    = (ushort_t*)(ws + ((size_t)16 << 20));
    ushort_t* kbuf  = (ushort_t*)(ws + ((size_t)24 << 20));
    ushort_t* vtb   = (ushort_t*)(ws + ((size_t)40 << 20));
    ushort_t* attno = xb;

    cast_kernel<<<8192, 256, 0, stream>>>(x, Wq, Wk, Wv, Wp, xb, Wqkvb, Wpb);

    dim3 g0(4096 / BM, 3072 / BN);
    gemm_bt<<<g0, 256, 0, stream>>>(xb, Wqkvb, 4096, 3072, 1024, 0,
                                    qb, kbuf, vtb, nullptr, nullptr);

    attn_kernel<<<512, 256, 0, stream>>>(qb, kbuf, vtb, attno);

    dim3 g1(4096 / BM, 1024 / BN);
    gemm_bt<<<g1, 256, 0, stream>>>(attno, Wpb, 4096, 1024, 1024, 1,
                                    nullptr, nullptr, nullptr, out, bp);
}

// Round 8
// 184.101 us; speedup vs baseline: 1.0880x; 1.0455x over previous
//
#include <hip/hip_runtime.h>
#include <stdint.h>

typedef unsigned short ushort_t;
typedef __attribute__((ext_vector_type(8))) __bf16 bf16x8;
typedef __attribute__((ext_vector_type(4))) float floatx4;
typedef __attribute__((ext_vector_type(2))) uint32_t uint32x2;

__device__ __forceinline__ ushort_t f2bf(float f) {
    uint32_t u = __builtin_bit_cast(uint32_t, f);
    u += 0x7fffu + ((u >> 16) & 1u);
    return (ushort_t)(u >> 16);
}

// async 16B global->LDS (deposit at ldsbase + lane*16; ldsbase wave-uniform)
typedef __attribute__((address_space(1))) const void glb_void;
typedef __attribute__((address_space(3))) void lds_void;
__device__ __forceinline__ void gld16(const void* g, void* l) {
    __builtin_amdgcn_global_load_lds((glb_void*)g, (lds_void*)l, 16, 0, 0);
}

// Q pre-scale: dh^-0.5 * log2(e) so attention softmax runs in exp2 domain.
#define QSCALE 0.18033688011112042f

// ---------------- cast: fp32 -> bf16 ----------------
__global__ void cast_kernel(const float* __restrict__ x,
                            const float* __restrict__ Wq, const float* __restrict__ Wk,
                            const float* __restrict__ Wv, const float* __restrict__ Wp,
                            ushort_t* __restrict__ xb, ushort_t* __restrict__ Wqkvb,
                            ushort_t* __restrict__ Wpb)
{
    const int64_t NX = 4194304, NW = 1048576;
    int64_t i4 = ((int64_t)blockIdx.x * blockDim.x + threadIdx.x) * 4;
    const float* src; ushort_t* dst; int64_t off;
    if (i4 < NX)            { src = x;  dst = xb;          off = i4; }
    else if (i4 < NX+NW)    { src = Wq; dst = Wqkvb;       off = i4 - NX; }
    else if (i4 < NX+2*NW)  { src = Wk; dst = Wqkvb + NW;  off = i4 - NX - NW; }
    else if (i4 < NX+3*NW)  { src = Wv; dst = Wqkvb + 2*NW;off = i4 - NX - 2*NW; }
    else                    { src = Wp; dst = Wpb;         off = i4 - NX - 3*NW; }
    float4 v = *(const float4*)(src + off);
    ushort4 o;
    o.x = f2bf(v.x); o.y = f2bf(v.y); o.z = f2bf(v.z); o.w = f2bf(v.w);
    *(ushort4*)(dst + off) = o;
}

// ---------------- bf16 GEMM: D = A @ B^T  (global_load_lds staging) ----------------
// mode 0: scatter Q,K -> [bh][s][d] (Q pre-scaled), V -> TRANSPOSED [bh][d][s]
// mode 1: fp32 out = D + bias
#define BM 128
#define BN 128
#define BK 32

__global__ __launch_bounds__(256, 3)
void gemm_bt(const ushort_t* __restrict__ A, const ushort_t* __restrict__ Bmat,
             int M, int N, int K, int mode,
             ushort_t* __restrict__ qb, ushort_t* __restrict__ kb, ushort_t* __restrict__ vtb,
             float* __restrict__ outf, const float* __restrict__ bias)
{
    __shared__ ushort_t As[BM * BK];   // 8KB, row-major, unpadded (lane-linear deposits)
    __shared__ ushort_t Bs[BN * BK];   // 8KB
    const int tid  = threadIdx.x;
    const int lane = tid & 63;
    const int wave = tid >> 6;
    const int m0 = blockIdx.x * BM;
    const int n0 = blockIdx.y * BN;
    const int wrow = (wave >> 1) * 64;
    const int wcol = (wave & 1) * 64;
    const int q_ = lane >> 4;
    const int ml = lane & 15;

    floatx4 acc[4][4];
    for (int i = 0; i < 4; i++) for (int j = 0; j < 4; j++) acc[i][j] = floatx4{0.f,0.f,0.f,0.f};

    // staging: 8 blocks of 1KB per tile (16 rows x 32 cols); wave w does blocks 2w,2w+1
    const int t0 = wave * 2, t1 = wave * 2 + 1;
    const int row_l = lane >> 2;         // 0..15
    const int col_l = (lane & 3) * 8;    // 0,8,16,24
    const ushort_t* Ag0 = A    + (int64_t)(m0 + t0*16 + row_l) * K + col_l;
    const ushort_t* Ag1 = A    + (int64_t)(m0 + t1*16 + row_l) * K + col_l;
    const ushort_t* Bg0 = Bmat + (int64_t)(n0 + t0*16 + row_l) * K + col_l;
    const ushort_t* Bg1 = Bmat + (int64_t)(n0 + t1*16 + row_l) * K + col_l;
    ushort_t* Al0 = As + t0*512; ushort_t* Al1 = As + t1*512;
    ushort_t* Bl0 = Bs + t0*512; ushort_t* Bl1 = Bs + t1*512;

    for (int k0 = 0; k0 < K; k0 += BK) {
        __syncthreads();
        gld16(Ag0 + k0, Al0);
        gld16(Ag1 + k0, Al1);
        gld16(Bg0 + k0, Bl0);
        gld16(Bg1 + k0, Bl1);
        __syncthreads();
        bf16x8 af[4], bf[4];
        for (int mt = 0; mt < 4; mt++)
            af[mt] = *(const bf16x8*)(As + (wrow + mt*16 + ml) * BK + q_*8);
        for (int nt = 0; nt < 4; nt++)
            bf[nt] = *(const bf16x8*)(Bs + (wcol + nt*16 + ml) * BK + q_*8);
        for (int mt = 0; mt < 4; mt++)
            for (int nt = 0; nt < 4; nt++)
                acc[mt][nt] = __builtin_amdgcn_mfma_f32_16x16x32_bf16(af[mt], bf[nt], acc[mt][nt], 0, 0, 0);
    }

    if (mode == 0) {
        for (int mt = 0; mt < 4; mt++) for (int nt = 0; nt < 4; nt++) {
            floatx4 v = acc[mt][nt];
            int col = n0 + wcol + nt*16 + ml;
            int which = col >> 10;
            int nn = col & 1023;
            int h = nn >> 6, d = nn & 63;
            if (which < 2) {
                ushort_t* dst = (which == 0) ? qb : kb;
                float sc = (which == 0) ? QSCALE : 1.0f;
                for (int r = 0; r < 4; r++) {
                    int rowg = m0 + wrow + mt*16 + q_*4 + r;
                    int b = rowg >> 11, s = rowg & 2047;
                    dst[(((int64_t)(b*16 + h) * 2048 + s) << 6) + d] = f2bf(v[r] * sc);
                }
            } else {
                int rowg0 = m0 + wrow + mt*16 + q_*4;
                int b = rowg0 >> 11, sbase = rowg0 & 2047;
                ushort4 o;
                o.x = f2bf(v[0]); o.y = f2bf(v[1]); o.z = f2bf(v[2]); o.w = f2bf(v[3]);
                *(ushort4*)(vtb + (((int64_t)(b*16 + h) * 64 + d) << 11) + sbase) = o;
            }
        }
    } else {
        for (int mt = 0; mt < 4; mt++) for (int nt = 0; nt < 4; nt++) {
            floatx4 v = acc[mt][nt];
            int col = n0 + wcol + nt*16 + ml;
            float bv = bias[col];
            for (int r = 0; r < 4; r++) {
                int rowg = m0 + wrow + mt*16 + q_*4 + r;
                outf[(int64_t)rowg * N + col] = v[r] + bv;
            }
        }
    }
}

// ---------------- fused masked flash attention: 4 waves x 16 q-rows, 1024 blocks ----
// r0 residency geometry (64 q-rows/block, LDS 50176B -> 3 blocks/CU, 12 waves/CU,
// grid 1024 >> 768 slots -> continuous backfill; heavy views dispatched first) +
// r3/r4-verified datapath: swapped QK^T (mfma(K,Q)) so lane holds
// P[q=ml][k=kt*16+4*q_+r] -> contiguous b64 P stores, scalar lsum, no setprio
// (lockstep waves, m190). r4/r7 showed grid==slots starves CUs at 1 wave/SIMD
// after the light partner block finishes — backfill is the fix.
__global__ __launch_bounds__(256, 3)
void attn_kernel(const ushort_t* __restrict__ Q, const ushort_t* __restrict__ Kb,
                 const ushort_t* __restrict__ Vt, ushort_t* __restrict__ Out)
{
    __shared__ ushort_t Kl[8192];        // 16KB: 16 blocks of 1KB (lane-linear)
    __shared__ ushort_t Vl[8192];        // 16KB
    __shared__ ushort_t Pl[4 * 16 * 136];// per-wave P tile [16 q][128 k], stride 136

    int bi = blockIdx.x;                 // 1024 blocks
    int bh = (bi & 7) + 8 * ((bi >> 3) & 3);   // low 3 bits -> XCD spread
    int qt = (bi >> 5) & 3;              // 64-row q piece
    int qv = 7 - (bi >> 7);              // heavy views first (qv=7 at t=0)
    int b = bh >> 4, h = bh & 15;
    int tid = threadIdx.x;
    int wave = tid >> 6, lane = tid & 63;
    int q_ = lane >> 4, ml = lane & 15;
    int rlane = lane & 15, clane = lane >> 4;
    int s0 = qv*256 + qt*64 + wave*16;   // this wave's 16 q-rows

    const ushort_t* Kbh = Kb + ((int64_t)bh << 17);
    const ushort_t* Vbh = Vt + ((int64_t)bh << 17);
    ushort_t* Pw = Pl + wave * (16 * 136);

    const ushort_t* Qp = Q + (((int64_t)bh*2048 + s0 + ml) << 6) + q_*8;
    bf16x8 aq0 = *(const bf16x8*)(Qp);
    bf16x8 aq1 = *(const bf16x8*)(Qp + 32);

    floatx4 o_acc[4];
    for (int i = 0; i < 4; i++) o_acc[i] = floatx4{0.f,0.f,0.f,0.f};
    float lsum = 0.f;                    // partial sum for q-row ml

    const int nviews = (qv < 2) ? 1 : (qv + 1);
    const int vfix = qv ^ 1;             // the single view when nviews==1

    for (int vi = 0; vi < nviews; vi++) {
        int kb0 = ((nviews == 1) ? vfix : vi) * 256;
        for (int ck = 0; ck < 2; ck++) {
            int koff = kb0 + ck * 128;

            __syncthreads();
            #pragma unroll
            for (int i = 0; i < 4; i++) {
                int id = wave*4 + i;
                const ushort_t* gk = Kbh + (((int64_t)(koff + (id >> 1)*16 + rlane)) << 6)
                                         + (id & 1)*32 + clane*8;
                gld16(gk, Kl + id*512);
                const ushort_t* gv = Vbh + ((int64_t)((id & 3)*16 + rlane) << 11)
                                         + koff + (id >> 2)*32 + clane*8;
                gld16(gv, Vl + id*512);
            }
            __syncthreads();

            // ---- S = K @ Q^T : lane -> q-row ml, keys kt*16 + 4*q_ + r ----
            #pragma unroll
            for (int kt = 0; kt < 8; kt++) {
                bf16x8 k0 = *(const bf16x8*)(Kl + kt*1024 + lane*8);
                bf16x8 k1 = *(const bf16x8*)(Kl + kt*1024 + 512 + lane*8);
                floatx4 cz = floatx4{0.f,0.f,0.f,0.f};
                cz = __builtin_amdgcn_mfma_f32_16x16x32_bf16(k0, aq0, cz, 0, 0, 0);
                cz = __builtin_amdgcn_mfma_f32_16x16x32_bf16(k1, aq1, cz, 0, 0, 0);

                float p0 = __builtin_amdgcn_exp2f(cz[0]);
                float p1 = __builtin_amdgcn_exp2f(cz[1]);
                float p2 = __builtin_amdgcn_exp2f(cz[2]);
                float p3 = __builtin_amdgcn_exp2f(cz[3]);
                lsum += (p0 + p1) + (p2 + p3);
                uint32x2 wv;
                wv[0] = (uint32_t)f2bf(p0) | ((uint32_t)f2bf(p1) << 16);
                wv[1] = (uint32_t)f2bf(p2) | ((uint32_t)f2bf(p3) << 16);
                *(uint32x2*)(Pw + ml*136 + kt*16 + q_*4) = wv;       // ds_write_b64
            }

            asm volatile("s_waitcnt lgkmcnt(0)" ::: "memory");  // wave-private P visible

            // ---- O += P @ V ----
            #pragma unroll
            for (int g = 0; g < 4; g++) {
                bf16x8 ap = *(const bf16x8*)(Pw + ml*136 + g*32 + q_*8);
                #pragma unroll
                for (int dt = 0; dt < 4; dt++) {
                    bf16x8 vv = *(const bf16x8*)(Vl + (g*4 + dt)*512 + lane*8);
                    o_acc[dt] = __builtin_amdgcn_mfma_f32_16x16x32_bf16(ap, vv, o_acc[dt], 0, 0, 0);
                }
            }
        }
    }

    // reduce l across the 4 quarters holding the same q-row (lanes ml + 16*q_)
    lsum += __shfl_xor(lsum, 16);
    lsum += __shfl_xor(lsum, 32);
    // o_acc rows are q = q_*4 + r; that row's total l lives at lane (q_*4 + r)
    float rinv[4];
    #pragma unroll
    for (int r = 0; r < 4; r++)
        rinv[r] = 1.0f / __shfl(lsum, q_*4 + r);

    // epilogue: Out[b][s][h*64+d] = o/l (bf16)
    #pragma unroll
    for (int dt = 0; dt < 4; dt++)
        #pragma unroll
        for (int r = 0; r < 4; r++) {
            float v = o_acc[dt][r] * rinv[r];
            int sr = s0 + q_*4 + r;
            Out[((int64_t)b*2048 + sr) * 1024 + h*64 + dt*16 + ml] = f2bf(v);
        }
}

extern "C" void kernel_launch(void* const* d_in, const int* in_sizes, int n_in,
                              void* d_out, int out_size, void* d_ws, size_t ws_size,
                              hipStream_t stream) {
    const float* x  = (const float*)d_in[0];
    const float* Wq = (const float*)d_in[1];
    const float* Wk = (const float*)d_in[2];
    const float* Wv = (const float*)d_in[3];
    const float* Wp = (const float*)d_in[4];
    const float* bp = (const float*)d_in[5];
    float* out = (float*)d_out;

    char* ws = (char*)d_ws;
    ushort_t* xb    = (ushort_t*)(ws);
    ushort_t* Wqkvb = (ushort_t*)(ws + ((size_t)8  << 20));
    ushort_t* Wpb   = (ushort_t*)(ws + ((size_t)14 << 20));
    ushort_t* qb    = (ushort_t*)(ws + ((size_t)16 << 20));
    ushort_t* kbuf  = (ushort_t*)(ws + ((size_t)24 << 20));
    ushort_t* vtb   = (ushort_t*)(ws + ((size_t)40 << 20));
    ushort_t* attno = xb;

    cast_kernel<<<8192, 256, 0, stream>>>(x, Wq, Wk, Wv, Wp, xb, Wqkvb, Wpb);

    dim3 g0(4096 / BM, 3072 / BN);
    gemm_bt<<<g0, 256, 0, stream>>>(xb, Wqkvb, 4096, 3072, 1024, 0,
                                    qb, kbuf, vtb, nullptr, nullptr);

    attn_kernel<<<1024, 256, 0, stream>>>(qb, kbuf, vtb, attno);

    dim3 g1(4096 / BM, 1024 / BN);
    gemm_bt<<<g1, 256, 0, stream>>>(attno, Wpb, 4096, 1024, 1024, 1,
                                    nullptr, nullptr, nullptr, out, bp);
}